// Round 16
// baseline (112.319 us; speedup 1.0000x reference)
//
#include <hip/hip_runtime.h>
#include <hip/hip_bf16.h>
#include <math.h>

typedef __bf16 bf16_t;
typedef __attribute__((ext_vector_type(8))) __bf16 bf16x8;
typedef __attribute__((ext_vector_type(4))) __bf16 bf16x4;
typedef __attribute__((ext_vector_type(4))) float f32x4;

#define B_DIM 2
#define S_DIM 2048
#define H_DIM 16
#define DK 64
#define DM 1024
#define KDIM 1024

#define MFMA(a, b, c) __builtin_amdgcn_mfma_f32_16x16x32_bf16((a), (b), (c), 0, 0, 0)

__device__ __forceinline__ void gload_lds16(const bf16_t* g, bf16_t* l) {
    __builtin_amdgcn_global_load_lds(
        (const __attribute__((address_space(1))) void*)g,
        (__attribute__((address_space(3))) void*)l, 16, 0, 0);
}

// ---------------- fp32 -> bf16 convert: x + 4 weights in ONE launch ----------------
__global__ void cvt_all(const float* __restrict__ x,
                        const float* __restrict__ wq, const float* __restrict__ wk,
                        const float* __restrict__ wv, const float* __restrict__ wo,
                        bf16_t* __restrict__ xb,
                        bf16_t* __restrict__ wqb, bf16_t* __restrict__ wkb,
                        bf16_t* __restrict__ wvb, bf16_t* __restrict__ wob) {
    const long NX = (long)B_DIM * S_DIM * DM;       // 4194304
    const long i = ((long)blockIdx.x * 256 + threadIdx.x) * 4;
    const float* s; bf16_t* d; long off;
    if (i < NX) { s = x; d = xb; off = i; }
    else {
        const long j = i - NX;
        const int wsel = (int)(j >> 20);            // NW = 1<<20
        off = j & ((1L << 20) - 1);
        switch (wsel) {
            case 0: s = wq; d = wqb; break;
            case 1: s = wk; d = wkb; break;
            case 2: s = wv; d = wvb; break;
            default: s = wo; d = wob; break;
        }
    }
    float4 v = *reinterpret_cast<const float4*>(s + off);
    bf16x4 o;
    o[0] = (__bf16)v.x; o[1] = (__bf16)v.y; o[2] = (__bf16)v.z; o[3] = (__bf16)v.w;
    *reinterpret_cast<bf16x4*>(d + off) = o;
}

// ---------------- GEMM: Y[m,n] = sum_k A[m,k] * B[n,k]  (B^T layout) ----------------
// (unchanged from R12: BK=64 XOR-swizzled K-loop + coalesced epilogues)
template <int MODE>
__global__ __launch_bounds__(256)
void gemm_bt(const bf16_t* __restrict__ A,
             const bf16_t* __restrict__ B0,
             const bf16_t* __restrict__ B1,
             const bf16_t* __restrict__ B2,
             bf16_t* __restrict__ outQ,
             bf16_t* __restrict__ outK,
             bf16_t* __restrict__ outVt,
             float* __restrict__ outF,
             const int* __restrict__ pos) {
    constexpr int CP = 136;
    constexpr int SELEMS = (MODE == 0) ? (128 * CP) : 16384;
    __shared__ bf16_t smem[SELEMS];
    bf16_t* As = smem;            // [128][64] swizzled
    bf16_t* Bs = smem + 8192;     // [128][64] swizzled
    bf16_t* Cs = smem;            // epilogue overlay

    const int t = threadIdx.x;
    const int z = blockIdx.z;
    const bf16_t* Bm = (MODE == 0) ? (z == 0 ? B0 : (z == 1 ? B1 : B2)) : B0;

    const int m0 = blockIdx.x * 128;
    const int n0 = blockIdx.y * 128;
    const int lane = t & 63;
    const int w = t >> 6;
    const int wr = w >> 1;
    const int wc = w & 1;

    f32x4 acc[4][4] = {};

    const bf16_t* Ag = A + (size_t)m0 * KDIM;
    const bf16_t* Bg = Bm + (size_t)n0 * KDIM;

    const int rr = lane & 15;
    const int ko = (lane >> 4) * 8;

    int rI[4], cI[4];
#pragma unroll
    for (int c = 0; c < 4; ++c) {
        const int i = t + c * 256;
        rI[c] = i >> 3;
        cI[c] = ((i & 7) ^ (rI[c] & 7)) * 8;
    }

    for (int k0 = 0; k0 < KDIM; k0 += 64) {
#pragma unroll
        for (int c = 0; c < 4; ++c) {
            const int i = t + c * 256;
            gload_lds16(Ag + (size_t)rI[c] * KDIM + k0 + cI[c], &As[i * 8]);
        }
#pragma unroll
        for (int c = 0; c < 4; ++c) {
            const int i = t + c * 256;
            gload_lds16(Bg + (size_t)rI[c] * KDIM + k0 + cI[c], &Bs[i * 8]);
        }
        __syncthreads();

        bf16x8 af[2][4], bfr[2][4];
#pragma unroll
        for (int kk = 0; kk < 2; ++kk) {
#pragma unroll
            for (int m = 0; m < 4; ++m) {
                const int r = wr * 64 + m * 16 + rr;
                af[kk][m] = *reinterpret_cast<const bf16x8*>(
                    &As[r * 64 + ((kk * 32 + ko) ^ ((r & 7) * 8))]);
            }
#pragma unroll
            for (int n = 0; n < 4; ++n) {
                const int r = wc * 64 + n * 16 + rr;
                bfr[kk][n] = *reinterpret_cast<const bf16x8*>(
                    &Bs[r * 64 + ((kk * 32 + ko) ^ ((r & 7) * 8))]);
            }
        }
        __builtin_amdgcn_s_setprio(1);
#pragma unroll
        for (int kk = 0; kk < 2; ++kk)
#pragma unroll
            for (int m = 0; m < 4; ++m)
#pragma unroll
                for (int n = 0; n < 4; ++n)
                    acc[m][n] = MFMA(af[kk][m], bfr[kk][n], acc[m][n]);
        __builtin_amdgcn_s_setprio(0);
        __syncthreads();
    }

    const int rlb = wr * 64 + (lane >> 4) * 4;
    const int clb = wc * 64 + (lane & 15);

    if (MODE == 0) {
        if (z < 2) {
#pragma unroll
            for (int m = 0; m < 4; ++m)
#pragma unroll
                for (int n = 0; n < 4; ++n)
#pragma unroll
                    for (int j = 0; j < 4; ++j)
                        Cs[(rlb + m * 16 + j) * CP + clb + n * 16] = (__bf16)acc[m][n][j];
            __syncthreads();

            bf16_t* dst = (z == 0) ? outQ : outK;
            const int dch = t & 7;
            const int srow = t >> 3;
            float fr[4];
#pragma unroll
            for (int i = 0; i < 4; ++i)
                fr[i] = exp2f((float)(dch * 4 + i) * -0.4152410118609203f);
#pragma unroll
            for (int p = 0; p < 4; ++p) {
                const int s_loc = p * 32 + srow;
                const int gm = m0 + s_loc;
                const int bb = gm >> 11, sg = gm & (S_DIM - 1);
                const float pv = (float)pos[sg];
                float csv[4], snv[4];
#pragma unroll
                for (int i = 0; i < 4; ++i) {
                    const float a = pv * fr[i];
                    csv[i] = cosf(a); snv[i] = sinf(a);
                }
#pragma unroll
                for (int hc = 0; hc < 2; ++hc) {
                    const bf16x8 vv = *reinterpret_cast<const bf16x8*>(
                        &Cs[s_loc * CP + hc * 64 + dch * 8]);
                    bf16x8 ov;
#pragma unroll
                    for (int i = 0; i < 4; ++i) {
                        const float v0 = (float)vv[2 * i], v1 = (float)vv[2 * i + 1];
                        ov[2 * i]     = (__bf16)(v0 * csv[i] - v1 * snv[i]);
                        ov[2 * i + 1] = (__bf16)(v0 * snv[i] + v1 * csv[i]);
                    }
                    const int h = (n0 >> 6) + hc;
                    *reinterpret_cast<bf16x8*>(
                        &dst[((size_t)(bb * H_DIM + h) * S_DIM + sg) * 64 + dch * 8]) = ov;
                }
            }
        } else {
#pragma unroll
            for (int m = 0; m < 4; ++m)
#pragma unroll
                for (int n = 0; n < 4; ++n) {
                    const int cl = clb + n * 16;
                    bf16x4 v4;
#pragma unroll
                    for (int j = 0; j < 4; ++j) v4[j] = (__bf16)acc[m][n][j];
                    *reinterpret_cast<bf16x4*>(&Cs[cl * CP + rlb + m * 16]) = v4;
                }
            __syncthreads();

            const int cl = t >> 1, sh = t & 1;
            const int cg = n0 + cl, h = cg >> 6, d = cg & 63;
            const int bb = m0 >> 11, s0g = m0 & (S_DIM - 1);
            bf16_t* vdst = &outVt[((size_t)(bb * H_DIM + h) * DK + d) * S_DIM + s0g + sh * 64];
#pragma unroll
            for (int i = 0; i < 8; ++i)
                *reinterpret_cast<bf16x8*>(&vdst[i * 8]) =
                    *reinterpret_cast<const bf16x8*>(&Cs[cl * CP + sh * 64 + i * 8]);
        }
    } else {
        const int rbase = m0 + rlb;
        const int cbase = n0 + clb;
#pragma unroll
        for (int m = 0; m < 4; ++m)
#pragma unroll
            for (int n = 0; n < 4; ++n)
#pragma unroll
                for (int j = 0; j < 4; ++j)
                    outF[(size_t)(rbase + m * 16 + j) * DM + cbase + n * 16] = acc[m][n][j];
    }
}

// ---------------- causal flash attention v12: KV-split work items ----------------
// 1536 items, longest-first, all duration <= 16 kv-tiles (flash-decoding split):
//   A [0,512):    qb>=16, kv [0,16)       -> fp32 partial slot (qb-16)*32+bh
//   B (even g):   qb>=16, kv [16,qb+1)    -> fp32 partial slot 512+...
//   C (odd g):    qb<=15, kv [0,qb+1)     -> final output direct
// Per-tile math identical to v11 (proven). Partials are UNNORMALIZED o + m,l.
__global__ __launch_bounds__(256, 4)
void attn_kernel(const bf16_t* __restrict__ Q, const bf16_t* __restrict__ Kg,
                 const bf16_t* __restrict__ Vt, bf16_t* __restrict__ O,
                 float* __restrict__ Po, float* __restrict__ Pml) {
    __shared__ bf16_t Ks[2][64 * 64];
    __shared__ bf16_t Vs[2][64 * 64];
    __shared__ bf16_t P_lds[4][16 * 64];

    const int t = threadIdx.x;
    const int lane = t & 63;
    const int w = t >> 6;                  // 0..3
    const int bid = blockIdx.x;

    int bh, qb, kvs, kve, slot;
    bool split;
    if (bid < 512) {                       // A: chunk0 of qb>=16 (16 tiles)
        bh = bid & 31; qb = 16 + (bid >> 5);
        kvs = 0; kve = 16; split = true; slot = (qb - 16) * 32 + bh;
    } else {
        const int k = bid - 512;
        const int g = k >> 5, i = k & 31;
        if ((g & 1) == 0) {                // B: chunk1 of qb>=16, longest first
            bh = i; qb = 31 - (g >> 1);
            kvs = 16; kve = qb + 1; split = true; slot = 512 + (qb - 16) * 32 + bh;
        } else {                           // C: qb<=15 whole, longest first
            bh = i; qb = 15 - (g >> 1);
            kvs = 0; kve = qb + 1; split = false; slot = 0;
        }
    }

    const int q0 = qb * 64 + w * 16;
    const int b = bh >> 4, h = bh & 15;
    const int rr = lane & 15;
    const int hi = lane >> 4;
    const int psw = (rr & 7) * 8;          // P col XOR swizzle

    const bf16_t* Kbh = Kg + (size_t)bh * S_DIM * DK;
    const bf16_t* Vbh = Vt + (size_t)bh * DK * S_DIM;   // [d][s]
    bf16_t* Pw = P_lds[w];

    const int i0 = t, i1 = t + 256;
    const int r0 = i0 >> 3, c0 = ((i0 & 7) ^ (r0 & 7)) * 8;
    const int r1 = i1 >> 3, c1 = ((i1 & 7) ^ (r1 & 7)) * 8;

    // Q fragments, folded scale = (1/8) * log2(e)
    const float QSCALE = 0.18033688011112042f;
    const bf16_t* Qp = Q + ((size_t)bh * S_DIM + q0) * DK;
    bf16x8 qf[2];
    qf[0] = *reinterpret_cast<const bf16x8*>(&Qp[rr * DK + hi * 8]);
    qf[1] = *reinterpret_cast<const bf16x8*>(&Qp[rr * DK + 32 + hi * 8]);
#pragma unroll
    for (int i = 0; i < 8; ++i) {
        qf[0][i] = (__bf16)((float)qf[0][i] * QSCALE);
        qf[1][i] = (__bf16)((float)qf[1][i] * QSCALE);
    }

    bf16x8 ones;
#pragma unroll
    for (int i = 0; i < 8; ++i) ones[i] = (__bf16)1.0f;

    f32x4 o[4] = {};
    f32x4 la = {};
    float m = -INFINITY;

    // prologue: stage tile kvs into buf 0
    gload_lds16(Kbh + (size_t)(kvs * 64 + r0) * DK + c0, &Ks[0][i0 * 8]);
    gload_lds16(Kbh + (size_t)(kvs * 64 + r1) * DK + c1, &Ks[0][i1 * 8]);
    gload_lds16(Vbh + (size_t)r0 * S_DIM + kvs * 64 + c0, &Vs[0][i0 * 8]);
    gload_lds16(Vbh + (size_t)r1 * S_DIM + kvs * 64 + c1, &Vs[0][i1 * 8]);
    __syncthreads();

    for (int tt = kvs; tt < kve; ++tt) {
        const int cur = (tt - kvs) & 1;
        const int kv0 = tt * 64;

        if (tt + 1 < kve) {
            const int kv1 = kv0 + 64;
            bf16_t* Kn = Ks[cur ^ 1];
            bf16_t* Vn = Vs[cur ^ 1];
            gload_lds16(Kbh + (size_t)(kv1 + r0) * DK + c0, &Kn[i0 * 8]);
            gload_lds16(Kbh + (size_t)(kv1 + r1) * DK + c1, &Kn[i1 * 8]);
            gload_lds16(Vbh + (size_t)r0 * S_DIM + kv1 + c0, &Vn[i0 * 8]);
            gload_lds16(Vbh + (size_t)r1 * S_DIM + kv1 + c1, &Vn[i1 * 8]);
        }
        const bf16_t* Kc = Ks[cur];
        const bf16_t* Vc = Vs[cur];

        // QK^T: s[t16][j] = S[kv = t16*16 + hi*4 + j][q = rr]
        f32x4 s[4] = {};
        __builtin_amdgcn_s_setprio(1);
#pragma unroll
        for (int t16 = 0; t16 < 4; ++t16) {
            const int r = t16 * 16 + rr;
            const int sw = (r & 7) * 8;
            bf16x8 kf0 = *reinterpret_cast<const bf16x8*>(&Kc[r * 64 + ((hi * 8) ^ sw)]);
            bf16x8 kf1 = *reinterpret_cast<const bf16x8*>(&Kc[r * 64 + ((32 + hi * 8) ^ sw)]);
            s[t16] = MFMA(kf0, qf[0], s[t16]);
            s[t16] = MFMA(kf1, qf[1], s[t16]);
        }
        __builtin_amdgcn_s_setprio(0);

        if (tt == qb) {
            const int qg = q0 + rr;
#pragma unroll
            for (int t16 = 0; t16 < 4; ++t16)
#pragma unroll
                for (int j = 0; j < 4; ++j)
                    if (kv0 + t16 * 16 + hi * 4 + j > qg) s[t16][j] = -INFINITY;
        }

        // softmax (lane-local defer-max trip, THR=8; l via ones-MFMA)
        f32x4 mv = s[0];
#pragma unroll
        for (int t16 = 1; t16 < 4; ++t16) {
            mv[0] = fmaxf(mv[0], s[t16][0]); mv[1] = fmaxf(mv[1], s[t16][1]);
            mv[2] = fmaxf(mv[2], s[t16][2]); mv[3] = fmaxf(mv[3], s[t16][3]);
        }
        const float mloc = fmaxf(fmaxf(mv[0], mv[1]), fmaxf(mv[2], mv[3]));
        if (__any(mloc - m > 8.0f)) {
            float mf = fmaxf(mloc, __shfl_xor(mloc, 16));
            mf = fmaxf(mf, __shfl_xor(mf, 32));
            const float mnew = fmaxf(m, mf);
            const float scale = exp2f(m - mnew);
#pragma unroll
            for (int i = 0; i < 4; ++i) la[i] *= scale;
#pragma unroll
            for (int db = 0; db < 4; ++db)
#pragma unroll
                for (int j = 0; j < 4; ++j) o[db][j] *= scale;
            m = mnew;
        }
#pragma unroll
        for (int t16 = 0; t16 < 4; ++t16) {
            bf16x4 pb;
#pragma unroll
            for (int j = 0; j < 4; ++j) pb[j] = (__bf16)exp2f(s[t16][j] - m);
            *reinterpret_cast<bf16x4*>(&Pw[rr * 64 + ((t16 * 16 + hi * 4) ^ psw)]) = pb;
        }

        bf16x8 pf0 = *reinterpret_cast<const bf16x8*>(&Pw[rr * 64 + ((hi * 8) ^ psw)]);
        bf16x8 pf1 = *reinterpret_cast<const bf16x8*>(&Pw[rr * 64 + ((32 + hi * 8) ^ psw)]);
        __builtin_amdgcn_s_setprio(1);
        la = MFMA(ones, pf0, la);
        la = MFMA(ones, pf1, la);
#pragma unroll
        for (int db = 0; db < 4; ++db) {
            const int vr = db * 16 + rr;
            const int sw = (vr & 7) * 8;
            bf16x8 vf0 = *reinterpret_cast<const bf16x8*>(&Vc[vr * 64 + ((hi * 8) ^ sw)]);
            bf16x8 vf1 = *reinterpret_cast<const bf16x8*>(&Vc[vr * 64 + ((32 + hi * 8) ^ sw)]);
            o[db] = MFMA(vf0, pf0, o[db]);
            o[db] = MFMA(vf1, pf1, o[db]);
        }
        __builtin_amdgcn_s_setprio(0);

        __syncthreads();
    }

    if (!split) {
        const float linv = 1.0f / la[0];
#pragma unroll
        for (int db = 0; db < 4; ++db) {
            bf16x4 ov;
#pragma unroll
            for (int j = 0; j < 4; ++j) ov[j] = (__bf16)(o[db][j] * linv);
            *reinterpret_cast<bf16x4*>(
                &O[((size_t)(b * S_DIM + q0 + rr)) * DM + h * DK + db * 16 + hi * 4]) = ov;
        }
    } else {
        // fp32 unnormalized partials: Po[slot][64 rows][64 d], Pml[slot][2][64]
        const int lrow = w * 16 + rr;
        float* po = Po + (size_t)slot * 4096 + lrow * 64;
#pragma unroll
        for (int db = 0; db < 4; ++db)
            *reinterpret_cast<f32x4*>(&po[db * 16 + hi * 4]) = o[db];
        if (hi == 0) {
            Pml[(size_t)slot * 128 + lrow] = m;
            Pml[(size_t)slot * 128 + 64 + lrow] = la[0];
        }
    }
}

// ---------------- combine: merge the two kv-chunks of each qb>=16 block ----------
__global__ __launch_bounds__(256)
void combine_kernel(const float* __restrict__ Po, const float* __restrict__ Pml,
                    bf16_t* __restrict__ O) {
    const int blk = blockIdx.x;            // 0..511 : (qb-16)*32 + bh
    const int qb = 16 + (blk >> 5);
    const int bh = blk & 31;
    const int b = bh >> 4, h = bh & 15;
    const int t = threadIdx.x;
    const int row = t >> 2;                // 0..63
    const int seg = (t & 3) * 16;          // 16 d-elems per thread

    const int p0 = blk, p1 = 512 + blk;
    const float m0 = Pml[(size_t)p0 * 128 + row];
    const float l0 = Pml[(size_t)p0 * 128 + 64 + row];
    const float m1 = Pml[(size_t)p1 * 128 + row];
    const float l1 = Pml[(size_t)p1 * 128 + 64 + row];
    const float M = fmaxf(m0, m1);
    const float w0 = exp2f(m0 - M), w1 = exp2f(m1 - M);
    const float inv = 1.0f / (l0 * w0 + l1 * w1);

    const float* o0 = Po + (size_t)p0 * 4096 + row * 64 + seg;
    const float* o1 = Po + (size_t)p1 * 4096 + row * 64 + seg;
    bf16_t* dst = &O[((size_t)(b * S_DIM + qb * 64 + row)) * DM + h * DK + seg];
    bf16x8 ov[2];
#pragma unroll
    for (int c = 0; c < 2; ++c) {
        const f32x4 a0 = *reinterpret_cast<const f32x4*>(o0 + c * 8);
        const f32x4 b0 = *reinterpret_cast<const f32x4*>(o1 + c * 8);
        const f32x4 a1 = *reinterpret_cast<const f32x4*>(o0 + c * 8 + 4);
        const f32x4 b1 = *reinterpret_cast<const f32x4*>(o1 + c * 8 + 4);
#pragma unroll
        for (int j = 0; j < 4; ++j) {
            ov[c][j]     = (__bf16)((a0[j] * w0 + b0[j] * w1) * inv);
            ov[c][j + 4] = (__bf16)((a1[j] * w0 + b1[j] * w1) * inv);
        }
    }
    *reinterpret_cast<bf16x8*>(dst)     = ov[0];
    *reinterpret_cast<bf16x8*>(dst + 8) = ov[1];
}

extern "C" void kernel_launch(void* const* d_in, const int* in_sizes, int n_in,
                              void* d_out, int out_size, void* d_ws, size_t ws_size,
                              hipStream_t stream) {
    const float* x  = (const float*)d_in[0];
    const float* Wq = (const float*)d_in[1];
    const float* Wk = (const float*)d_in[2];
    const float* Wv = (const float*)d_in[3];
    const float* Wo = (const float*)d_in[4];
    const int* pos  = (const int*)d_in[5];
    float* out = (float*)d_out;

    char* ws = (char*)d_ws;
    bf16_t* xb  = (bf16_t*)(ws);
    bf16_t* Wqb = (bf16_t*)(ws + (8u << 20));
    bf16_t* Wkb = (bf16_t*)(ws + (10u << 20));
    bf16_t* Wvb = (bf16_t*)(ws + (12u << 20));
    bf16_t* Wob = (bf16_t*)(ws + (14u << 20));
    bf16_t* Qb  = (bf16_t*)(ws + (16u << 20));
    bf16_t* Kb  = (bf16_t*)(ws + (24u << 20));
    bf16_t* Vtb = (bf16_t*)(ws + (32u << 20));
    bf16_t* Ab  = (bf16_t*)(ws);                  // attn output, reuses xb region
    float*  Po  = (float*)(ws + (40u << 20));     // 16 MB fp32 partial o
    float*  Pml = (float*)(ws + (56u << 20));     // 0.5 MB partial m,l

    const int NX = B_DIM * S_DIM * DM;
    const int NW = DM * DM;
    const int NTOT = NX + 4 * NW;  // 8388608

    cvt_all<<<NTOT / 1024, 256, 0, stream>>>(x, Wq, Wk, Wv, Wo,
                                             xb, Wqb, Wkb, Wvb, Wob);

    gemm_bt<0><<<dim3(32, 8, 3), 256, 0, stream>>>(xb, Wqb, Wkb, Wvb,
                                                   Qb, Kb, Vtb, nullptr, pos);

    attn_kernel<<<1536, 256, 0, stream>>>(Qb, Kb, Vtb, Ab, Po, Pml);
    combine_kernel<<<512, 256, 0, stream>>>(Po, Pml, Ab);

    gemm_bt<1><<<dim3(32, 8, 1), 256, 0, stream>>>(Ab, Wob, nullptr, nullptr,
                                                   nullptr, nullptr, nullptr, out, pos);
}